// Round 12
// baseline (224.730 us; speedup 1.0000x reference)
//
#include <hip/hip_runtime.h>

typedef __bf16 bf16x8 __attribute__((ext_vector_type(8)));
typedef float f32x4 __attribute__((ext_vector_type(4)));
typedef float f32x16 __attribute__((ext_vector_type(16)));

__device__ __forceinline__ unsigned short f2bf(float x) {
  union { float f; unsigned u; } a; a.f = x;
  unsigned r = a.u + 0x7FFFu + ((a.u >> 16) & 1u);
  return (unsigned short)(r >> 16);
}

__device__ __forceinline__ float exp2f_fast(float x) {
  return __builtin_amdgcn_exp2f(x);
}

__device__ __forceinline__ unsigned cvtpk_bf16(float lo, float hi) {
  unsigned r;
  asm("v_cvt_pk_bf16_f32 %0, %1, %2" : "=v"(r) : "v"(lo), "v"(hi));
  return r;
}

__device__ __forceinline__ int swap23(int x) {  // swap bits 2 and 3
  return (x & ~12) | ((x & 4) << 1) | ((x & 8) >> 1);
}

// ---------------------------------------------------------------------------
// Fused prep (unchanged from round 6 — verified passing).
//  [0,4096):    selection -> sm bitmasks
//  [4096,4352): K -> Kt fragment-tiled bf16: Kt[kv][s][j][lane] (16B slots)
//  [4352,4608): V -> Vt fragment-tiled bf16: Vt[kv][s][j'][lane]
// ---------------------------------------------------------------------------
__global__ __launch_bounds__(256) void prep_kernel(const float* __restrict__ k,
                                                   const float* __restrict__ v,
                                                   const float* __restrict__ p,
                                                   unsigned short* __restrict__ Kt,
                                                   unsigned short* __restrict__ Vt,
                                                   unsigned* __restrict__ sm) {
  const int bx = blockIdx.x;
  if (bx < 4096) {
    // --- selection, rank-based top-k (one wave per (kv, m))
    const int wid = bx * 4 + (threadIdx.x >> 6);
    const int lane = threadIdx.x & 63;
    const int kv = wid >> 11;
    const int m = wid & 2047;
    const int rb = m >> 6;
    const int s = lane & 31;
    const int c0 = 4 * s - 1;
    float best = -1.f;
    for (int g = 0; g < 2; ++g) {
      int h = kv * 4 + (lane >> 5) * 2 + g;
      const float* pr = p + ((size_t)h * 2048 + m) * 127;
      float acc = 0.f;
      if (c0 >= 0) acc = fmaf(pr[c0], 1.f, acc);
      acc = fmaf(pr[c0 + 1], 2.f, acc);
      acc = fmaf(pr[c0 + 2], 2.f, acc);
      acc = fmaf(pr[c0 + 3], 2.f, acc);
      if (c0 + 4 < 127) acc = fmaf(pr[c0 + 4], 1.f, acc);
      best = fmaxf(best, acc);
    }
    best = fmaxf(best, __shfl_xor(best, 32));
    const int rbm1 = rb > 0 ? rb - 1 : 0;
    if (s == 0 || s == rb || s == rbm1) best = 999999.0f;
    const int half = lane & 32;
    int cnt = 0;
#pragma unroll
    for (int o = 1; o <= 16; ++o) {
      int oo = half ? (o + 16) : o;
      int os = (s + oo) & 31;
      float ov = __shfl(best, half | os);
      bool gr = (ov > best) || (ov == best && os < s);
      cnt += (gr && oo < 32) ? 1 : 0;
    }
    int rank = cnt + __shfl_xor(cnt, 32);
    const int kmax = min(rb + 1, 16);
    unsigned long long bal = __ballot(rank < kmax);
    if (lane == 0) sm[(size_t)kv * 2048 + m] = (unsigned)(bal & 0xffffffffu);
  } else if (bx < 4352) {
    // --- K fragment tiler
    const int kvs = bx - 4096;                 // kv*32 + s
    const int kv = kvs >> 5, s = kvs & 31;
    const int lane = threadIdx.x & 63;
    const int jg = threadIdx.x >> 6;
    const int c = lane & 31, hb = lane >> 5;
    const int posl = swap23(c);
    unsigned short* dst = Kt + ((size_t)kvs << 13);
#pragma unroll
    for (int jj = 0; jj < 4; ++jj) {
      int j = jg * 4 + jj;
      int pos = s * 64 + ((j >> 3) << 5) + posl;
      int d0 = ((j & 7) << 4) + (hb << 3);
      const float* src = k + (((size_t)pos * 8 + kv) << 7) + d0;
      float4 a = *(const float4*)src;
      float4 b = *(const float4*)(src + 4);
      union { bf16x8 w; unsigned short u[8]; } t;
      t.u[0] = f2bf(a.x); t.u[1] = f2bf(a.y); t.u[2] = f2bf(a.z); t.u[3] = f2bf(a.w);
      t.u[4] = f2bf(b.x); t.u[5] = f2bf(b.y); t.u[6] = f2bf(b.z); t.u[7] = f2bf(b.w);
      *(bf16x8*)(dst + ((j * 64 + lane) << 3)) = t.w;
    }
  } else {
    // --- V fragment tiler (transposed gather)
    const int kvs = bx - 4352;
    const int kv = kvs >> 5, s = kvs & 31;
    const int lane = threadIdx.x & 63;
    const int jg = threadIdx.x >> 6;
    const int c = lane & 31, hb = lane >> 5;
    unsigned short* dst = Vt + ((size_t)kvs << 13);
#pragma unroll
    for (int jj = 0; jj < 4; ++jj) {
      int j = jg * 4 + jj;
      int db = j >> 2, kk = j & 3;
      int d = (db << 5) + c;
      int pos0 = s * 64 + (kk << 4) + (hb << 3);
      union { bf16x8 w; unsigned short u[8]; } t;
#pragma unroll
      for (int i = 0; i < 8; ++i)
        t.u[i] = f2bf(v[(((size_t)(pos0 + i) * 8 + kv) << 7) + d]);
      *(bf16x8*)(dst + ((j * 64 + lane) << 3)) = t.w;
    }
  }
}

// ---------------------------------------------------------------------------
// Attention round 12: d-split waves. Each task (8 rows x 4 heads, one kv) is
// computed by TWO independent waves: both do full QK + softmax (bit-identical
// lrun -> consistent normalization), each does PV for HALF of d (oacc[2],
// vf[8]) and writes its disjoint half of O. No merge, no LDS, no barriers.
// 4096 waves -> 4 waves/SIMD (2x round 6 TLP). VGPR ~90 < 128 cap: NO SPILL
// (spill-corruption rule from rounds 8-11). QK/softmax duplication is cheap:
// both pipes were idle (~21%).
// Grid 1024 WGs x 256: wg = zp*8+kv; quadrant-reversed f(zp) makes the 4
// co-resident WGs' rb-sums constant (load-balance).
// ---------------------------------------------------------------------------
__global__ __launch_bounds__(256, 4) void attn_kernel(
    const unsigned short* __restrict__ Kt,
    const unsigned short* __restrict__ Vt,
    const float* __restrict__ q,
    const unsigned* __restrict__ sm,
    float* __restrict__ out) {
  const int wg = blockIdx.x;
  const int kv = wg & 7;
  const int zp = wg >> 3;                      // 0..127
  const int qd = zp >> 5, pos = zp & 31;
  const int fz = qd * 32 + ((qd & 1) ? (31 - pos) : pos);  // rb-sum-constant map
  const int tid = threadIdx.x;
  const int w = tid >> 6, lane = tid & 63;
  const int zi = fz * 2 + (w >> 1);            // task z-index 0..255
  const int half = w & 1;                      // d-half of this wave
  const int m0 = zi * 8;
  const int rb = zi >> 3;
  const int c = lane & 31, hb = lane >> 5;
  const int row = m0 + (c & 7);
  const int head = kv * 4 + (c >> 3);

  // Q B-frags (scale * log2e folded in): lane holds col (row,head), k=16ks+8hb+i
  const float qs = 0.08838834764831845f * 1.4426950408889634f;
  bf16x8 qf[8];
  {
    const float* qp = q + ((size_t)row * 32 + head) * 128 + hb * 8;
#pragma unroll
    for (int ks = 0; ks < 8; ++ks) {
      float4 av = *(const float4*)(qp + ks * 16);
      float4 bv = *(const float4*)(qp + ks * 16 + 4);
      union { bf16x8 v; unsigned w4[4]; } t;
      t.w4[0] = cvtpk_bf16(av.x * qs, av.y * qs);
      t.w4[1] = cvtpk_bf16(av.z * qs, av.w * qs);
      t.w4[2] = cvtpk_bf16(bv.x * qs, bv.y * qs);
      t.w4[3] = cvtpk_bf16(bv.z * qs, bv.w * qs);
      qf[ks] = t.v;
    }
  }
  const unsigned selr = sm[(size_t)kv * 2048 + row];
  unsigned aW = selr;
  aW |= __shfl_xor(aW, 1);
  aW |= __shfl_xor(aW, 2);
  aW |= __shfl_xor(aW, 4);           // union over the task's 8 rows
  aW &= (2u << rb) - 1u;             // causal cap (rb=31 wraps to all-ones)

  f32x16 oacc[2];                    // HALF of O: d in [half*64, half*64+64)
#pragma unroll
  for (int i = 0; i < 2; ++i)
#pragma unroll
    for (int e = 0; e < 16; ++e) oacc[i][e] = 0.f;
  float lrun = 0.f;

  const unsigned short* Kb = Kt + ((size_t)(kv * 32) << 13);
  const unsigned short* Vb = Vt + ((size_t)(kv * 32) << 13) + ((size_t)(half * 8 * 64) << 3);

  unsigned bits = aW;
  while (bits) {
    const int s = __builtin_ctz(bits);
    bits &= bits - 1;
    const unsigned short* kt = Kb + ((size_t)s << 13);
    const unsigned short* vt = Vb + ((size_t)s << 13);
    // --- K fragments: 16 coalesced 1KB loads
    bf16x8 kf[16];
#pragma unroll
    for (int j = 0; j < 16; ++j)
      kf[j] = *(const bf16x8*)(kt + ((j * 64 + lane) << 3));
    // --- QK^T (swapped: A=K, B=Q); acc pos-ascending per lane via swap23 tiling
    f32x16 a0 = {}, a1 = {};
#pragma unroll
    for (int ks = 0; ks < 8; ++ks)
      a0 = __builtin_amdgcn_mfma_f32_32x32x16_bf16(kf[ks], qf[ks], a0, 0, 0, 0);
#pragma unroll
    for (int ks = 0; ks < 8; ++ks)
      a1 = __builtin_amdgcn_mfma_f32_32x32x16_bf16(kf[8 + ks], qf[ks], a1, 0, 0, 0);
    // --- V fragments (this wave's d-half only); latency hides under softmax
    bf16x8 vf[8];
#pragma unroll
    for (int j = 0; j < 8; ++j)
      vf[j] = *(const bf16x8*)(vt + ((j * 64 + lane) << 3));
    // --- mask + exp (fixed reference m=0)
    int lim = ((selr >> s) & 1u) ? ((s == rb) ? (row & 63) : 63) : -1;
    int limadj = lim - 8 * hb;
    float pv[32];
#pragma unroll
    for (int j = 0; j < 32; ++j) {
      int P0 = ((j >> 4) << 5) + (((j >> 3) & 1) << 4) + (j & 7);
      float x = (j < 16) ? a0[j & 15] : a1[j & 15];
      pv[j] = exp2f_fast((P0 <= limadj) ? x : -3.0e38f);
    }
    float s0[8];
#pragma unroll
    for (int j = 0; j < 8; ++j)
      s0[j] = (pv[4 * j] + pv[4 * j + 1]) + (pv[4 * j + 2] + pv[4 * j + 3]);
    float psum = ((s0[0] + s0[1]) + (s0[2] + s0[3])) + ((s0[4] + s0[5]) + (s0[6] + s0[7]));
    psum += __shfl_xor(psum, 32);
    lrun += psum;
    // --- P B-frags: pos-sequential pack, 16 cvt_pk
    bf16x8 pf[4];
#pragma unroll
    for (int kk = 0; kk < 4; ++kk) {
      union { bf16x8 v; unsigned w4[4]; } t;
      t.w4[0] = cvtpk_bf16(pv[8 * kk + 0], pv[8 * kk + 1]);
      t.w4[1] = cvtpk_bf16(pv[8 * kk + 2], pv[8 * kk + 3]);
      t.w4[2] = cvtpk_bf16(pv[8 * kk + 4], pv[8 * kk + 5]);
      t.w4[3] = cvtpk_bf16(pv[8 * kk + 6], pv[8 * kk + 7]);
      pf[kk] = t.v;
    }
    // --- PV for this d-half (swapped: A=V^T, B=P^T)
#pragma unroll
    for (int jp = 0; jp < 8; ++jp)
      oacc[jp >> 2] = __builtin_amdgcn_mfma_f32_32x32x16_bf16(vf[jp], pf[jp & 3], oacc[jp >> 2], 0, 0, 0);
  }
  // --- epilogue: O[row,head][d = half*64 + db*32 + 8*rg + 4*hb + e]
  const float inv = 1.f / lrun;
  float* op = out + ((size_t)row * 32 + head) * 128 + half * 64;
#pragma unroll
  for (int db = 0; db < 2; ++db) {
#pragma unroll
    for (int rg = 0; rg < 4; ++rg) {
      float4 o4;
      o4.x = oacc[db][4 * rg + 0] * inv;
      o4.y = oacc[db][4 * rg + 1] * inv;
      o4.z = oacc[db][4 * rg + 2] * inv;
      o4.w = oacc[db][4 * rg + 3] * inv;
      *(float4*)&op[db * 32 + rg * 8 + hb * 4] = o4;
    }
  }
}

extern "C" void kernel_launch(void* const* d_in, const int* in_sizes, int n_in,
                              void* d_out, int out_size, void* d_ws, size_t ws_size,
                              hipStream_t stream) {
  const float* q = (const float*)d_in[0];
  const float* k = (const float*)d_in[1];
  const float* v = (const float*)d_in[2];
  const float* p = (const float*)d_in[3];
  float* out = (float*)d_out;
  unsigned short* Kt = (unsigned short*)d_ws;
  unsigned short* Vt = (unsigned short*)((char*)d_ws + (size_t)4 * 1024 * 1024);
  unsigned* sm = (unsigned*)((char*)d_ws + (size_t)8 * 1024 * 1024);

  prep_kernel<<<4608, 256, 0, stream>>>(k, v, p, Kt, Vt, sm);
  attn_kernel<<<1024, 256, 0, stream>>>(Kt, Vt, q, sm, out);
}

// Round 13
// 95.469 us; speedup vs baseline: 2.3540x; 2.3540x over previous
//
#include <hip/hip_runtime.h>

typedef __bf16 bf16x8 __attribute__((ext_vector_type(8)));
typedef float f32x4 __attribute__((ext_vector_type(4)));
typedef float f32x16 __attribute__((ext_vector_type(16)));

__device__ __forceinline__ unsigned short f2bf(float x) {
  union { float f; unsigned u; } a; a.f = x;
  unsigned r = a.u + 0x7FFFu + ((a.u >> 16) & 1u);
  return (unsigned short)(r >> 16);
}

__device__ __forceinline__ float exp2f_fast(float x) {
  return __builtin_amdgcn_exp2f(x);
}

__device__ __forceinline__ unsigned cvtpk_bf16(float lo, float hi) {
  unsigned r;
  asm("v_cvt_pk_bf16_f32 %0, %1, %2" : "=v"(r) : "v"(lo), "v"(hi));
  return r;
}

__device__ __forceinline__ int swap23(int x) {  // swap bits 2 and 3
  return (x & ~12) | ((x & 4) << 1) | ((x & 8) >> 1);
}

// ---------------------------------------------------------------------------
// Fused prep (unchanged — verified passing).
//  [0,4096):    selection -> sm bitmasks
//  [4096,4352): K -> Kt fragment-tiled bf16: Kt[kv][s][j][lane] (16B slots)
//  [4352,4608): V -> Vt fragment-tiled bf16: Vt[kv][s][j'][lane]
// ---------------------------------------------------------------------------
__global__ __launch_bounds__(256) void prep_kernel(const float* __restrict__ k,
                                                   const float* __restrict__ v,
                                                   const float* __restrict__ p,
                                                   unsigned short* __restrict__ Kt,
                                                   unsigned short* __restrict__ Vt,
                                                   unsigned* __restrict__ sm) {
  const int bx = blockIdx.x;
  if (bx < 4096) {
    // --- selection, rank-based top-k (one wave per (kv, m))
    const int wid = bx * 4 + (threadIdx.x >> 6);
    const int lane = threadIdx.x & 63;
    const int kv = wid >> 11;
    const int m = wid & 2047;
    const int rb = m >> 6;
    const int s = lane & 31;
    const int c0 = 4 * s - 1;
    float best = -1.f;
    for (int g = 0; g < 2; ++g) {
      int h = kv * 4 + (lane >> 5) * 2 + g;
      const float* pr = p + ((size_t)h * 2048 + m) * 127;
      float acc = 0.f;
      if (c0 >= 0) acc = fmaf(pr[c0], 1.f, acc);
      acc = fmaf(pr[c0 + 1], 2.f, acc);
      acc = fmaf(pr[c0 + 2], 2.f, acc);
      acc = fmaf(pr[c0 + 3], 2.f, acc);
      if (c0 + 4 < 127) acc = fmaf(pr[c0 + 4], 1.f, acc);
      best = fmaxf(best, acc);
    }
    best = fmaxf(best, __shfl_xor(best, 32));
    const int rbm1 = rb > 0 ? rb - 1 : 0;
    if (s == 0 || s == rb || s == rbm1) best = 999999.0f;
    const int half = lane & 32;
    int cnt = 0;
#pragma unroll
    for (int o = 1; o <= 16; ++o) {
      int oo = half ? (o + 16) : o;
      int os = (s + oo) & 31;
      float ov = __shfl(best, half | os);
      bool gr = (ov > best) || (ov == best && os < s);
      cnt += (gr && oo < 32) ? 1 : 0;
    }
    int rank = cnt + __shfl_xor(cnt, 32);
    const int kmax = min(rb + 1, 16);
    unsigned long long bal = __ballot(rank < kmax);
    if (lane == 0) sm[(size_t)kv * 2048 + m] = (unsigned)(bal & 0xffffffffu);
  } else if (bx < 4352) {
    // --- K fragment tiler
    const int kvs = bx - 4096;                 // kv*32 + s
    const int kv = kvs >> 5, s = kvs & 31;
    const int lane = threadIdx.x & 63;
    const int jg = threadIdx.x >> 6;
    const int c = lane & 31, hb = lane >> 5;
    const int posl = swap23(c);
    unsigned short* dst = Kt + ((size_t)kvs << 13);
#pragma unroll
    for (int jj = 0; jj < 4; ++jj) {
      int j = jg * 4 + jj;
      int pos = s * 64 + ((j >> 3) << 5) + posl;
      int d0 = ((j & 7) << 4) + (hb << 3);
      const float* src = k + (((size_t)pos * 8 + kv) << 7) + d0;
      float4 a = *(const float4*)src;
      float4 b = *(const float4*)(src + 4);
      union { bf16x8 w; unsigned short u[8]; } t;
      t.u[0] = f2bf(a.x); t.u[1] = f2bf(a.y); t.u[2] = f2bf(a.z); t.u[3] = f2bf(a.w);
      t.u[4] = f2bf(b.x); t.u[5] = f2bf(b.y); t.u[6] = f2bf(b.z); t.u[7] = f2bf(b.w);
      *(bf16x8*)(dst + ((j * 64 + lane) << 3)) = t.w;
    }
  } else {
    // --- V fragment tiler (transposed gather)
    const int kvs = bx - 4352;
    const int kv = kvs >> 5, s = kvs & 31;
    const int lane = threadIdx.x & 63;
    const int jg = threadIdx.x >> 6;
    const int c = lane & 31, hb = lane >> 5;
    unsigned short* dst = Vt + ((size_t)kvs << 13);
#pragma unroll
    for (int jj = 0; jj < 4; ++jj) {
      int j = jg * 4 + jj;
      int db = j >> 2, kk = j & 3;
      int d = (db << 5) + c;
      int pos0 = s * 64 + (kk << 4) + (hb << 3);
      union { bf16x8 w; unsigned short u[8]; } t;
#pragma unroll
      for (int i = 0; i < 8; ++i)
        t.u[i] = f2bf(v[(((size_t)(pos0 + i) * 8 + kv) << 7) + d]);
      *(bf16x8*)(dst + ((j * 64 + lane) << 3)) = t.w;
    }
  }
}

// ---------------------------------------------------------------------------
// Attention round 13: round-12's verified d-split (each task = 8 rows x 4
// heads computed by TWO independent waves, each doing full QK+softmax and PV
// for half of d — no merge, no barriers, disjoint output writes) with the
// occupancy cap corrected: launch_bounds(256,3) -> unified VGPR budget ~170
// vs ~180 demand -> spill shrinks from ~60 regs (round 12's (256,4), which
// caused 6x FETCH inflation from scratch traffic) to ~0-15. 3 waves/SIMD
// resident, 1.5x round-6 TLP.
// ---------------------------------------------------------------------------
__global__ __launch_bounds__(256, 3) void attn_kernel(
    const unsigned short* __restrict__ Kt,
    const unsigned short* __restrict__ Vt,
    const float* __restrict__ q,
    const unsigned* __restrict__ sm,
    float* __restrict__ out) {
  const int wg = blockIdx.x;
  const int kv = wg & 7;
  const int zp = wg >> 3;                      // 0..127
  const int qd = zp >> 5, pos = zp & 31;
  const int fz = qd * 32 + ((qd & 1) ? (31 - pos) : pos);  // rb-sum-constant map
  const int tid = threadIdx.x;
  const int w = tid >> 6, lane = tid & 63;
  const int zi = fz * 2 + (w >> 1);            // task z-index 0..255
  const int half = w & 1;                      // d-half of this wave
  const int m0 = zi * 8;
  const int rb = zi >> 3;
  const int c = lane & 31, hb = lane >> 5;
  const int row = m0 + (c & 7);
  const int head = kv * 4 + (c >> 3);

  // Q B-frags (scale * log2e folded in): lane holds col (row,head), k=16ks+8hb+i
  const float qs = 0.08838834764831845f * 1.4426950408889634f;
  bf16x8 qf[8];
  {
    const float* qp = q + ((size_t)row * 32 + head) * 128 + hb * 8;
#pragma unroll
    for (int ks = 0; ks < 8; ++ks) {
      float4 av = *(const float4*)(qp + ks * 16);
      float4 bv = *(const float4*)(qp + ks * 16 + 4);
      union { bf16x8 v; unsigned w4[4]; } t;
      t.w4[0] = cvtpk_bf16(av.x * qs, av.y * qs);
      t.w4[1] = cvtpk_bf16(av.z * qs, av.w * qs);
      t.w4[2] = cvtpk_bf16(bv.x * qs, bv.y * qs);
      t.w4[3] = cvtpk_bf16(bv.z * qs, bv.w * qs);
      qf[ks] = t.v;
    }
  }
  const unsigned selr = sm[(size_t)kv * 2048 + row];
  unsigned aW = selr;
  aW |= __shfl_xor(aW, 1);
  aW |= __shfl_xor(aW, 2);
  aW |= __shfl_xor(aW, 4);           // union over the task's 8 rows
  aW &= (2u << rb) - 1u;             // causal cap (rb=31 wraps to all-ones)

  f32x16 oacc[2];                    // HALF of O: d in [half*64, half*64+64)
#pragma unroll
  for (int i = 0; i < 2; ++i)
#pragma unroll
    for (int e = 0; e < 16; ++e) oacc[i][e] = 0.f;
  float lrun = 0.f;

  const unsigned short* Kb = Kt + ((size_t)(kv * 32) << 13);
  const unsigned short* Vb = Vt + ((size_t)(kv * 32) << 13) + ((size_t)(half * 8 * 64) << 3);

  unsigned bits = aW;
  while (bits) {
    const int s = __builtin_ctz(bits);
    bits &= bits - 1;
    const unsigned short* kt = Kb + ((size_t)s << 13);
    const unsigned short* vt = Vb + ((size_t)s << 13);
    // --- K fragments: 16 coalesced 1KB loads
    bf16x8 kf[16];
#pragma unroll
    for (int j = 0; j < 16; ++j)
      kf[j] = *(const bf16x8*)(kt + ((j * 64 + lane) << 3));
    // --- QK^T (swapped: A=K, B=Q); acc pos-ascending per lane via swap23 tiling
    f32x16 a0 = {}, a1 = {};
#pragma unroll
    for (int ks = 0; ks < 8; ++ks)
      a0 = __builtin_amdgcn_mfma_f32_32x32x16_bf16(kf[ks], qf[ks], a0, 0, 0, 0);
#pragma unroll
    for (int ks = 0; ks < 8; ++ks)
      a1 = __builtin_amdgcn_mfma_f32_32x32x16_bf16(kf[8 + ks], qf[ks], a1, 0, 0, 0);
    // --- V fragments (this wave's d-half only); latency hides under softmax
    bf16x8 vf[8];
#pragma unroll
    for (int j = 0; j < 8; ++j)
      vf[j] = *(const bf16x8*)(vt + ((j * 64 + lane) << 3));
    // --- mask + exp (fixed reference m=0)
    int lim = ((selr >> s) & 1u) ? ((s == rb) ? (row & 63) : 63) : -1;
    int limadj = lim - 8 * hb;
    float pv[32];
#pragma unroll
    for (int j = 0; j < 32; ++j) {
      int P0 = ((j >> 4) << 5) + (((j >> 3) & 1) << 4) + (j & 7);
      float x = (j < 16) ? a0[j & 15] : a1[j & 15];
      pv[j] = exp2f_fast((P0 <= limadj) ? x : -3.0e38f);
    }
    float s0[8];
#pragma unroll
    for (int j = 0; j < 8; ++j)
      s0[j] = (pv[4 * j] + pv[4 * j + 1]) + (pv[4 * j + 2] + pv[4 * j + 3]);
    float psum = ((s0[0] + s0[1]) + (s0[2] + s0[3])) + ((s0[4] + s0[5]) + (s0[6] + s0[7]));
    psum += __shfl_xor(psum, 32);
    lrun += psum;
    // --- P B-frags: pos-sequential pack, 16 cvt_pk
    bf16x8 pf[4];
#pragma unroll
    for (int kk = 0; kk < 4; ++kk) {
      union { bf16x8 v; unsigned w4[4]; } t;
      t.w4[0] = cvtpk_bf16(pv[8 * kk + 0], pv[8 * kk + 1]);
      t.w4[1] = cvtpk_bf16(pv[8 * kk + 2], pv[8 * kk + 3]);
      t.w4[2] = cvtpk_bf16(pv[8 * kk + 4], pv[8 * kk + 5]);
      t.w4[3] = cvtpk_bf16(pv[8 * kk + 6], pv[8 * kk + 7]);
      pf[kk] = t.v;
    }
    // --- PV for this d-half (swapped: A=V^T, B=P^T)
#pragma unroll
    for (int jp = 0; jp < 8; ++jp)
      oacc[jp >> 2] = __builtin_amdgcn_mfma_f32_32x32x16_bf16(vf[jp], pf[jp & 3], oacc[jp >> 2], 0, 0, 0);
  }
  // --- epilogue: O[row,head][d = half*64 + db*32 + 8*rg + 4*hb + e]
  const float inv = 1.f / lrun;
  float* op = out + ((size_t)row * 32 + head) * 128 + half * 64;
#pragma unroll
  for (int db = 0; db < 2; ++db) {
#pragma unroll
    for (int rg = 0; rg < 4; ++rg) {
      float4 o4;
      o4.x = oacc[db][4 * rg + 0] * inv;
      o4.y = oacc[db][4 * rg + 1] * inv;
      o4.z = oacc[db][4 * rg + 2] * inv;
      o4.w = oacc[db][4 * rg + 3] * inv;
      *(float4*)&op[db * 32 + rg * 8 + hb * 4] = o4;
    }
  }
}

extern "C" void kernel_launch(void* const* d_in, const int* in_sizes, int n_in,
                              void* d_out, int out_size, void* d_ws, size_t ws_size,
                              hipStream_t stream) {
  const float* q = (const float*)d_in[0];
  const float* k = (const float*)d_in[1];
  const float* v = (const float*)d_in[2];
  const float* p = (const float*)d_in[3];
  float* out = (float*)d_out;
  unsigned short* Kt = (unsigned short*)d_ws;
  unsigned short* Vt = (unsigned short*)((char*)d_ws + (size_t)4 * 1024 * 1024);
  unsigned* sm = (unsigned*)((char*)d_ws + (size_t)8 * 1024 * 1024);

  prep_kernel<<<4608, 256, 0, stream>>>(k, v, p, Kt, Vt, sm);
  attn_kernel<<<1024, 256, 0, stream>>>(Kt, Vt, q, sm, out);
}